// Round 1
// 311.490 us; speedup vs baseline: 1.0441x; 1.0441x over previous
//
#include <hip/hip_runtime.h>
#include <hip/hip_bf16.h>

// ---------------------------------------------------------------------------
// FakeFlexOlmoSparseMlp: top-2 MoE over 8 experts, H=1024, 8192 tokens.
// R5: double-buffered K-loop with counted vmcnt (T3/T4 "minimum 2-phase").
// R4 post-mortem: MfmaUtil 12.5%, VALUBusy 7.7%, HBM 20% -> latency-bound.
// Single-buffered k-steps drained vmcnt(0) at the 2nd barrier every step;
// with only ~1.4 blocks/CU resident there was no cross-block cover, so each
// of the 16 k-steps paid full global latency serially. Now: stage k-step
// t+1 into buf^1 BEFORE computing t, raw s_barrier + s_waitcnt vmcnt(4)
// (never 0 in-loop) so 4 loads/wave stay in flight across barriers.
// LDS 32KB -> 64KB (2 blocks/CU); within-block pipelining replaces
// cross-block overlap.
// ---------------------------------------------------------------------------

#define HD   1024
#define NTOK 8192
#define NEXP 8
#define BM   128
#define BN   128
#define BK   64
#define ZROW 8192     // sentinel row in x_bf16 filled with zeros (pad slots)
#define MAXP 17408    // 16384 pairs + 8*128 max padding = 136 tiles of 128
#define EP_LDSW 136   // epilogue LDS row stride (shorts); 272B = 16B-aligned

typedef __attribute__((ext_vector_type(8))) short  vshort8;
typedef __attribute__((ext_vector_type(4))) short  vshort4;
typedef __attribute__((ext_vector_type(4))) float  vfloat4;

typedef __attribute__((address_space(1))) const unsigned gas_uint;
typedef __attribute__((address_space(3))) unsigned       las_uint;

__device__ __forceinline__ void gld16(const void* g, void* l) {
    // async global->LDS, 16B/lane; LDS dest = wave-uniform base + lane*16
    __builtin_amdgcn_global_load_lds((gas_uint*)g, (las_uint*)l, 16, 0, 0);
}

__device__ __forceinline__ short bf16r(float f) {
    union { float f; unsigned u; } a; a.f = f;
    unsigned r = a.u + 0x7FFFu + ((a.u >> 16) & 1u);   // round-to-nearest-even
    return (short)(r >> 16);
}

// --- K1: zero meta, pair_token -> ZROW sentinel, zero the ZROW row ---------
__global__ void init_kernel(int* counts, int* fill, int* pair_token, short* xb) {
    int i = blockIdx.x * 256 + threadIdx.x;
    if (i < NEXP) { counts[i] = 0; fill[i] = 0; }
    if (i < MAXP) pair_token[i] = ZROW;
    if (i < HD / 8) {
        vshort8 z = {0, 0, 0, 0, 0, 0, 0, 0};
        *(vshort8*)(xb + (size_t)ZROW * HD + i * 8) = z;
    }
}

// --- K2: router fused with residual-copy + bf16 cast -----------------------
__global__ __launch_bounds__(256) void router_kernel(
    const float* __restrict__ x, const float* __restrict__ rw,
    float* __restrict__ out, short* __restrict__ xb,
    float* __restrict__ probs_out, int2* __restrict__ tok_top,
    float2* __restrict__ tok_w, int* __restrict__ counts) {
    __shared__ float rws[NEXP * HD];
    __shared__ int hist[NEXP];
    int t = threadIdx.x;
    if (t < NEXP) hist[t] = 0;
    for (int j = 0; j < 8; ++j) {
        int idx = j * 1024 + t * 4;
        *(vfloat4*)(rws + idx) = *(const vfloat4*)(rw + idx);
    }
    __syncthreads();
    int wave = t >> 6, lane = t & 63;
    for (int it = 0; it < 8; ++it) {
        int token = blockIdx.x * 32 + it * 4 + wave;
        const float* xr = x + (size_t)token * HD;
        float part[NEXP];
#pragma unroll
        for (int e = 0; e < NEXP; ++e) part[e] = 0.f;
        for (int j = 0; j < 4; ++j) {
            int off = j * 256 + lane * 4;
            vfloat4 xv = *(const vfloat4*)(xr + off);
            *(vfloat4*)(out + (size_t)token * HD + off) = xv;   // residual init
            vshort4 bq;
            bq.x = bf16r(xv.x); bq.y = bf16r(xv.y); bq.z = bf16r(xv.z); bq.w = bf16r(xv.w);
            *(vshort4*)(xb + (size_t)token * HD + off) = bq;
#pragma unroll
            for (int e = 0; e < NEXP; ++e) {
                vfloat4 wv = *(const vfloat4*)(rws + e * HD + off);
                part[e] += xv.x * wv.x + xv.y * wv.y + xv.z * wv.z + xv.w * wv.w;
            }
        }
#pragma unroll
        for (int e = 0; e < NEXP; ++e)
            for (int off = 32; off; off >>= 1)
                part[e] += __shfl_xor(part[e], off, 64);
        if (lane == 0) {
            float m = part[0];
#pragma unroll
            for (int e = 1; e < NEXP; ++e) m = fmaxf(m, part[e]);
            float p[NEXP], s = 0.f;
#pragma unroll
            for (int e = 0; e < NEXP; ++e) { p[e] = expf(part[e] - m); s += p[e]; }
            float inv = 1.f / s;
#pragma unroll
            for (int e = 0; e < NEXP; ++e) {
                p[e] *= inv;
                probs_out[(size_t)token * NEXP + e] = p[e];
            }
            int i0 = 0;
#pragma unroll
            for (int e = 1; e < NEXP; ++e) if (p[e] > p[i0]) i0 = e;  // ties -> lowest idx
            int i1 = (i0 == 0) ? 1 : 0;
#pragma unroll
            for (int e = 0; e < NEXP; ++e) if (e != i0 && p[e] > p[i1]) i1 = e;
            float s2 = 1.f / (p[i0] + p[i1]);
            tok_top[token] = make_int2(i0, i1);
            tok_w[token]   = make_float2(p[i0] * s2, p[i1] * s2);
            atomicAdd(&hist[i0], 1);
            atomicAdd(&hist[i1], 1);
        }
    }
    __syncthreads();
    if (t < NEXP) atomicAdd(&counts[t], hist[t]);
}

// --- K3: scatter pairs into expert buckets (inline offsets from counts) ----
__global__ __launch_bounds__(256) void scatter_kernel(
    const int2* __restrict__ tok_top, const float2* __restrict__ tok_w,
    const int* __restrict__ counts, int* fill,
    int* __restrict__ pair_token, float* __restrict__ pair_w) {
    __shared__ int lhist[NEXP];
    __shared__ int lbase[NEXP];
    int t = threadIdx.x;
    if (t < NEXP) lhist[t] = 0;
    __syncthreads();
    int offs[NEXP];
    {
        int acc = 0;
#pragma unroll
        for (int f = 0; f < NEXP; ++f) {
            offs[f] = acc;
            acc += (counts[f] + 127) & ~127;
        }
    }
    int token = blockIdx.x * 256 + t;
    int2 ti = tok_top[token];
    float2 tw = tok_w[token];
    int r0 = atomicAdd(&lhist[ti.x], 1);
    int r1 = atomicAdd(&lhist[ti.y], 1);
    __syncthreads();
    if (t < NEXP) lbase[t] = atomicAdd(&fill[t], lhist[t]);
    __syncthreads();
    int s0 = offs[ti.x] + lbase[ti.x] + r0;
    pair_token[s0] = token; pair_w[s0] = tw.x;
    int s1 = offs[ti.y] + lbase[ti.y] + r1;
    pair_token[s1] = token; pair_w[s1] = tw.y;
}

// --- K4: fp32 W1+W2 -> bf16 in MFMA-fragment chunk order -------------------
// Chunk C = ((e*64 + ng)*32 + kc): 64 lanes x 16B; lane l holds
// W[e][ng*16 + (l&15)][kc*32 + (l>>4)*8 .. +7].
__global__ void convw_kernel(const float* __restrict__ W1, const float* __restrict__ W2,
                             short* __restrict__ D1, short* __restrict__ D2) {
    size_t t = (size_t)blockIdx.x * 256 + threadIdx.x;
    const size_t PER = (size_t)NEXP * HD * HD / 8;
    const float* src = W1; short* dst = D1;
    if (t >= PER) { t -= PER; src = W2; dst = D2; }
    size_t C = t >> 6;
    int l  = (int)(t & 63);
    int kc = (int)(C & 31);
    int ng = (int)((C >> 5) & 63);
    int ei = (int)(C >> 11);
    int n = ng * 16 + (l & 15);
    int k = kc * 32 + (l >> 4) * 8;
    const float* s = src + ((size_t)ei * HD + n) * HD + k;
    vfloat4 a = *(const vfloat4*)s;
    vfloat4 b = *(const vfloat4*)(s + 4);
    vshort8 o;
    o[0] = bf16r(a.x); o[1] = bf16r(a.y); o[2] = bf16r(a.z); o[3] = bf16r(a.w);
    o[4] = bf16r(b.x); o[5] = bf16r(b.y); o[6] = bf16r(b.z); o[7] = bf16r(b.w);
    *(vshort8*)(dst + t * 8) = o;
}

// --- K5/K6: grouped NT-GEMM, 8 waves/block, double-buffered pipeline -------
// LDS (shorts): sA(b) = smem + b*8192, sB(b) = smem + 16384 + b*8192 -> 64KB.
// Wave w: rows wm*64 (wm=w>>2), cols wn*32 (wn=w&3); acc[4][2].
// Per k-step: wave stages its A chunks (g=w, s=0,1) + B chunks (h=w, s=0,1)
// for step t+1 into buf^1, waits vmcnt(4) (own step-t loads done, next 4 in
// flight), raw s_barrier, ds_read+MFMA on buf, compiler-barrier, s_barrier.
// MODE 0: A rows gathered via pair_token; epi relu(acc+b1)->LDS->chunked h1.
// MODE 1: A = chunk-ordered h1; epi atomicAdd out += w*(acc+b2).
template <int MODE>
__global__ __launch_bounds__(512, 4) void moe_gemm(
    const short* __restrict__ A, const short* __restrict__ Bw,
    const float* __restrict__ bias, const int* __restrict__ pair_token,
    const float* __restrict__ pair_w, const int* __restrict__ counts,
    short* __restrict__ h1sw_out, float* __restrict__ out) {
    __shared__ short smem[32768];   // 64 KB: A dbuf [0..16383], B dbuf [16384..32767]

    const int row0 = blockIdx.x * BM;
    // inline padded prefix over counts -> expert id + total
    int e = 0;
    {
        int csum = 0;
#pragma unroll
        for (int f = 0; f < NEXP; ++f) {
            int p = (counts[f] + 127) & ~127;
            if (csum + p <= row0) e = f + 1;
            csum += p;
        }
        if (row0 >= csum) return;       // past padded total
    }

    const int t = threadIdx.x;
    const int wave = t >> 6, lane = t & 63;
    const int wm = wave >> 2, wn = wave & 3;
    const int quad = lane >> 4, l16 = lane & 15;
    const int colb = blockIdx.y * BN;

    // per-lane global source pointers (at k0 = 0)
    const char* agp;
    if (MODE == 0) {
        int tok = pair_token[row0 + wave * 16 + l16];
        agp = (const char*)A + (size_t)tok * (HD * 2) + quad * 16;
    } else {
        agp = (const char*)A + (((size_t)(row0 >> 4) + wave) * 32) * 1024 + lane * 16;
    }
    const char* bgp = (const char*)Bw +
        (((size_t)e * 64 + (colb >> 4) + wave) * 32) * 1024 + lane * 16;

    vfloat4 acc[4][2];
#pragma unroll
    for (int i = 0; i < 4; ++i)
#pragma unroll
        for (int j = 0; j < 2; ++j)
            acc[i][j] = (vfloat4){0.f, 0.f, 0.f, 0.f};

#define STAGE(bsel, kk0)                                                      \
    {                                                                         \
        const int kc_ = (kk0) >> 5;                                           \
        short* sa_ = smem + (bsel) * 8192;                                    \
        short* sb_ = smem + 16384 + (bsel) * 8192;                            \
        _Pragma("unroll")                                                     \
        for (int s = 0; s < 2; ++s) {                                         \
            const char* ga_ = (MODE == 0)                                     \
                ? (agp + (size_t)(kk0) * 2 + s * 64)                          \
                : (agp + (size_t)(kc_ + s) * 1024);                           \
            gld16(ga_, sa_ + (wave * 2 + s) * 512);                           \
            gld16(bgp + (size_t)(kc_ + s) * 1024, sb_ + (wave * 2 + s) * 512);\
        }                                                                     \
    }

    STAGE(0, 0)                              // prologue: 4 loads in flight
    int cur = 0;
    for (int kt = 0; kt < HD / BK; ++kt) {
        if (kt < HD / BK - 1) {
            STAGE(cur ^ 1, (kt + 1) * BK)    // issue next tile: 8 outstanding
            asm volatile("s_waitcnt vmcnt(4)" ::: "memory");  // step-kt loads landed
        } else {
            asm volatile("s_waitcnt vmcnt(0)" ::: "memory");  // drain last tile
        }
        __builtin_amdgcn_s_barrier();        // all waves' tile kt in LDS
        asm volatile("" ::: "memory");
        const short* sa = smem + cur * 8192;
        const short* sb = smem + 16384 + cur * 8192;
#pragma unroll
        for (int s = 0; s < 2; ++s) {
            vshort8 af[4], bfr[2];
#pragma unroll
            for (int i = 0; i < 4; ++i)
                af[i] = *(const vshort8*)(sa + ((wm * 4 + i) * 2 + s) * 512 + lane * 8);
#pragma unroll
            for (int j = 0; j < 2; ++j)
                bfr[j] = *(const vshort8*)(sb + ((wn * 2 + j) * 2 + s) * 512 + lane * 8);
#pragma unroll
            for (int i = 0; i < 4; ++i)
#pragma unroll
                for (int j = 0; j < 2; ++j)
                    acc[i][j] = __builtin_amdgcn_mfma_f32_16x16x32_bf16(af[i], bfr[j], acc[i][j], 0, 0, 0);
        }
        asm volatile("" ::: "memory");
        __builtin_amdgcn_s_barrier();        // reads of buf[cur] done before restage
        cur ^= 1;
    }
#undef STAGE

    if (MODE == 0) {
        // epilogue: relu(acc+b1) -> bf16 LDS tile -> chunk-ordered h1sw
        __syncthreads();
#pragma unroll
        for (int j = 0; j < 2; ++j) {
            int col = wn * 32 + j * 16 + l16;
            float bv = bias[e * HD + colb + col];
#pragma unroll
            for (int i = 0; i < 4; ++i) {
                int rl = wm * 64 + i * 16 + quad * 4;
#pragma unroll
                for (int reg = 0; reg < 4; ++reg) {
                    float v = acc[i][j][reg] + bv;
                    v = v > 0.f ? v : 0.f;
                    smem[(rl + reg) * EP_LDSW + col] = bf16r(v);
                }
            }
        }
        __syncthreads();
        int lrow = wave * 16 + l16;
#pragma unroll
        for (int kk = 0; kk < 4; ++kk) {
            vshort8 v = *(const vshort8*)(smem + lrow * EP_LDSW + kk * 32 + quad * 8);
            size_t chunk = ((size_t)((row0 >> 4) + wave) * 32) + ((colb >> 5) + kk);
            *(vshort8*)(h1sw_out + chunk * 512 + lane * 8) = v;
        }
    } else {
        int tok[4][4]; float wv[4][4];
#pragma unroll
        for (int i = 0; i < 4; ++i)
#pragma unroll
            for (int reg = 0; reg < 4; ++reg) {
                int r = row0 + wm * 64 + i * 16 + quad * 4 + reg;
                tok[i][reg] = pair_token[r];
                wv[i][reg] = pair_w[r];
            }
#pragma unroll
        for (int j = 0; j < 2; ++j) {
            int col = colb + wn * 32 + j * 16 + l16;
            float bv = bias[e * HD + col];
#pragma unroll
            for (int i = 0; i < 4; ++i)
#pragma unroll
                for (int reg = 0; reg < 4; ++reg)
                    if (tok[i][reg] < ZROW)
                        atomicAdd(out + (size_t)tok[i][reg] * HD + col,
                                  wv[i][reg] * (acc[i][j][reg] + bv));
        }
    }
}

extern "C" void kernel_launch(void* const* d_in, const int* in_sizes, int n_in,
                              void* d_out, int out_size, void* d_ws, size_t ws_size,
                              hipStream_t stream) {
    const float* x  = (const float*)d_in[0];
    const float* rw = (const float*)d_in[1];
    const float* W1 = (const float*)d_in[2];
    const float* b1 = (const float*)d_in[3];
    const float* W2 = (const float*)d_in[4];
    const float* b2 = (const float*)d_in[5];
    float* out   = (float*)d_out;                // [8192,1024] residual+moe
    float* probs = out + (size_t)NTOK * HD;      // [8192,8]

    char* ws = (char*)d_ws;
    short* xb = (short*)ws;            ws += (size_t)(NTOK + 1) * HD * 2;
    short* h1 = (short*)ws;            ws += (size_t)MAXP * HD * 2;
    int*   pair_token = (int*)ws;      ws += MAXP * 4;
    float* pair_w     = (float*)ws;    ws += MAXP * 4;
    int*   counts = (int*)ws;          ws += 256;
    int*   fill   = (int*)ws;          ws += 256;
    int2*   tok_top = (int2*)ws;       ws += NTOK * 8;
    float2* tok_w   = (float2*)ws;     ws += NTOK * 8;
    short* w1sw = (short*)ws;          ws += (size_t)NEXP * HD * HD * 2;
    short* w2sw = (short*)ws;          ws += (size_t)NEXP * HD * HD * 2;
    (void)ws_size;

    init_kernel<<<MAXP / 256, 256, 0, stream>>>(counts, fill, pair_token, xb);
    router_kernel<<<NTOK / 32, 256, 0, stream>>>(x, rw, out, xb, probs,
                                                 tok_top, tok_w, counts);
    scatter_kernel<<<NTOK / 256, 256, 0, stream>>>(tok_top, tok_w, counts, fill,
                                                   pair_token, pair_w);
    int cg = (int)(2 * ((size_t)NEXP * HD * HD / 8) / 256);   // 8192 blocks
    convw_kernel<<<cg, 256, 0, stream>>>(W1, W2, w1sw, w2sw);
    dim3 gg(MAXP / BM, HD / BN);       // 136 x 8; blocks past padded total exit
    moe_gemm<0><<<gg, 512, 0, stream>>>(xb, w1sw, b1, pair_token, pair_w, counts, h1, nullptr);
    moe_gemm<1><<<gg, 512, 0, stream>>>(h1, w2sw, b2, pair_token, pair_w, counts, nullptr, out);
}